// Round 7
// baseline (1447.852 us; speedup 1.0000x reference)
//
#include <hip/hip_runtime.h>
#include <math.h>

#define BATCH 2048
#define TLEN 200
#define NCH 64
#define HID 120

// ---- ws float-offset layout (all regions fully written before read; no atomics anywhere) ----
#define C1_OFF 0         // [0..3] cs1, [4..11] cA           (16)
#define C2_OFF 16        // [0..7] cs2, [8..15] cd2          (16)
#define C3_OFF 32        // [0..7] s3,  [8..15] d3           (16)
#define CO_OFF 48        // [0..7] mean_o, [8..15] rsqrt_o   (16)
#define CL_OFF 64        // A[8*240]=1920, then Bsum[8] at CL_OFF+1920 (pad to 2048)
#define P1_OFF 2048      // k1 partials: 2048 blocks x 8
#define P2_OFF 18432     // k2 partials: 1600 x 16
#define P3_OFF 44032     // k3 partials: 512 x 16
#define PO_OFF 52224     // k5 partials: 512 x 2
#define PL_OFF 53248     // k4 partials: 256 x 480
#define P_OFF  176128    // pooled pre-BN3 seq: 8*10*2048
#define HB_OFF 339968    // head outputs: 8*2048
#define A_OFF  356352    // big region: conv2-raw/z2 (B*200*8), then feats (8*B*240)

__device__ __forceinline__ float eluf(float v){ return v > 0.f ? v : __expf(v) - 1.f; }
__device__ __forceinline__ float sigmf(float x){ return 1.f/(1.f + __expf(-x)); }
__device__ __forceinline__ float tanhf_fast(float x){ return 1.f - 2.f/(__expf(2.f*x) + 1.f); }

// ---------------- K1: conv1(101 over T) + ELU + BN1 partial stats + conv2 raw dot ----------------
__global__ __launch_bounds__(256) void k1_conv(const float* __restrict__ x,
    const float* __restrict__ w1, const float* __restrict__ b1,
    const float* __restrict__ w2, float* __restrict__ rbuf, float* __restrict__ partial1)
{
  __shared__ float w2s[8*65];
  __shared__ float ebuf[4][32*65];
  __shared__ float red[4][8];
  const int tid = threadIdx.x, lane = tid & 63, wid = tid >> 6;
  for (int i = tid; i < 512; i += 256) w2s[(i>>6)*65 + (i&63)] = w2[i];
  __syncthreads();
  const int b = blockIdx.x;
  const float* xb = x + (size_t)b * (TLEN*NCH);
  float s1[4] = {0,0,0,0}, ss1[4] = {0,0,0,0};
  float* eb = ebuf[wid];
  for (int cnk = wid; cnk < 25; cnk += 4) {
    const int t0 = cnk * 8;
    float win[8];
    #pragma unroll
    for (int j = 0; j < 8; ++j) {
      int ti = t0 - 50 + j;
      win[j] = ((unsigned)ti < (unsigned)TLEN) ? xb[ti*NCH + lane] : 0.f;
    }
    float acc[8][4];
    #pragma unroll
    for (int j = 0; j < 8; ++j) {
      acc[j][0] = b1[0]; acc[j][1] = b1[1]; acc[j][2] = b1[2]; acc[j][3] = b1[3];
    }
    for (int kb = 0; kb < 101; kb += 8) {
      #pragma unroll
      for (int kk = 0; kk < 8; ++kk) {
        const int k = kb + kk;
        if (k < 101) {
          const float wk0 = w1[k], wk1 = w1[101+k], wk2 = w1[202+k], wk3 = w1[303+k];
          #pragma unroll
          for (int j = 0; j < 8; ++j) {
            const float xv = win[(kk + j) & 7];
            acc[j][0] += wk0 * xv; acc[j][1] += wk1 * xv;
            acc[j][2] += wk2 * xv; acc[j][3] += wk3 * xv;
          }
          int ti = t0 + k - 42;
          win[kk] = (k < 100 && (unsigned)ti < (unsigned)TLEN) ? xb[ti*NCH + lane] : 0.f;
        }
      }
    }
    #pragma unroll
    for (int j = 0; j < 8; ++j) {
      #pragma unroll
      for (int c = 0; c < 4; ++c) {
        float e = eluf(acc[j][c]);
        s1[c] += e; ss1[c] += e*e;
        eb[(j*4+c)*65 + lane] = e;
      }
    }
    __threadfence_block();
    {
      const int tt = lane >> 3, oo = lane & 7, cc = oo >> 1;
      float racc = 0.f;
      #pragma unroll 8
      for (int ch = 0; ch < 64; ++ch)
        racc += w2s[oo*65 + ch] * eb[(tt*4 + cc)*65 + ch];
      rbuf[((size_t)b*TLEN + t0 + tt)*8 + oo] = racc;
    }
    __threadfence_block();
  }
  #pragma unroll
  for (int c = 0; c < 4; ++c)
    for (int m = 32; m; m >>= 1) { s1[c] += __shfl_xor(s1[c], m); ss1[c] += __shfl_xor(ss1[c], m); }
  if (lane == 0) {
    #pragma unroll
    for (int c = 0; c < 4; ++c) { red[wid][c] = s1[c]; red[wid][4+c] = ss1[c]; }
  }
  __syncthreads();
  if (tid < 8)
    partial1[(size_t)blockIdx.x*8 + tid] = red[0][tid] + red[1][tid] + red[2][tid] + red[3][tid];
}

// ---------------- KR1: fold BN1 stats (double, fixed order, no cross-lane ops) ----------------
__global__ __launch_bounds__(64) void kr1(const float* __restrict__ partial1,
    const float* __restrict__ g1, const float* __restrict__ be1,
    const float* __restrict__ w2, const float* __restrict__ b2, float* __restrict__ C)
{
  __shared__ double part[64];
  __shared__ double dst[4];
  const int lane = threadIdx.x;
  const int j = lane & 7, chunk = lane >> 3;      // 8 chunks x 256 blocks
  double s = 0.0;
  for (int i = 0; i < 256; ++i) s += (double)partial1[(size_t)(chunk*256 + i)*8 + j];
  part[lane] = s;
  __syncthreads();
  if (lane < 4) {
    double S = 0.0, SS = 0.0;
    for (int cc = 0; cc < 8; ++cc) { S += part[cc*8 + lane]; SS += part[cc*8 + 4 + lane]; }
    const double N = 2048.0*200.0*64.0;
    double m = S/N, var = fmax(SS/N - m*m, 1e-20);
    double sc = (double)g1[lane] / sqrt(var);
    C[C1_OFF + lane] = (float)sc;
    dst[lane] = (double)be1[lane] - m*sc;
  }
  __syncthreads();
  if (lane < 8) {
    double wsum = 0.0;
    for (int ch = 0; ch < 64; ++ch) wsum += (double)w2[lane*64 + ch];
    C[C1_OFF + 4 + lane] = (float)(dst[lane>>1] * wsum + (double)b2[lane]);
  }
}

// ---------------- K2: z2 = ELU(cs1*r + cA) in-place; BN2 partial stats ----------------
__global__ __launch_bounds__(256) void k2_elu(const float* __restrict__ C,
    float* __restrict__ rz, float* __restrict__ partial2)
{
  __shared__ float red[4][16];
  const int tid = threadIdx.x, lane = tid & 63, wid = tid >> 6;
  float cs1v[4], cAv[8];
  #pragma unroll
  for (int c = 0; c < 4; ++c) cs1v[c] = C[C1_OFF + c];
  #pragma unroll
  for (int o = 0; o < 8; ++o) cAv[o] = C[C1_OFF + 4 + o];
  const size_t idx = (size_t)blockIdx.x * 256 + tid;
  float4 r0 = *(const float4*)(rz + idx*8);
  float4 r1 = *(const float4*)(rz + idx*8 + 4);
  float rr[8] = {r0.x,r0.y,r0.z,r0.w,r1.x,r1.y,r1.z,r1.w};
  float z[8];
  #pragma unroll
  for (int o = 0; o < 8; ++o) z[o] = eluf(cs1v[o>>1]*rr[o] + cAv[o]);
  *(float4*)(rz + idx*8)     = make_float4(z[0],z[1],z[2],z[3]);
  *(float4*)(rz + idx*8 + 4) = make_float4(z[4],z[5],z[6],z[7]);
  float sv[8], sq_[8];
  #pragma unroll
  for (int o = 0; o < 8; ++o) { sv[o] = z[o]; sq_[o] = z[o]*z[o]; }
  #pragma unroll
  for (int o = 0; o < 8; ++o)
    for (int m = 32; m; m >>= 1) { sv[o] += __shfl_xor(sv[o], m); sq_[o] += __shfl_xor(sq_[o], m); }
  if (lane == 0) {
    #pragma unroll
    for (int o = 0; o < 8; ++o) { red[wid][o] = sv[o]; red[wid][8+o] = sq_[o]; }
  }
  __syncthreads();
  if (tid < 16)
    partial2[(size_t)blockIdx.x*16 + tid] = red[0][tid]+red[1][tid]+red[2][tid]+red[3][tid];
}

// ---------------- KR2: fold BN2 stats ----------------
__global__ __launch_bounds__(256) void kr2(const float* __restrict__ partial2,
    const float* __restrict__ g2, const float* __restrict__ be2, float* __restrict__ C)
{
  __shared__ double dred[256];
  const int tid = threadIdx.x;
  const int t = tid & 15, chunk = tid >> 4;       // 16 chunks x 100
  double s = 0.0;
  for (int i = 0; i < 100; ++i) s += (double)partial2[(size_t)(chunk*100 + i)*16 + t];
  dred[tid] = s;
  __syncthreads();
  if (tid < 8) {
    double S = 0.0, SS = 0.0;
    for (int ch = 0; ch < 16; ++ch) { S += dred[ch*16 + tid]; SS += dred[ch*16 + 8 + tid]; }
    const double N = 2048.0*200.0;
    double m = S/N, var = fmax(SS/N - m*m, 1e-20);
    double sc = (double)g2[tid] / sqrt(var);
    C[C2_OFF + tid] = (float)sc;
    C[C2_OFF + 8 + tid] = (float)((double)be2[tid] - m*sc);
  }
}

// ---------------- K3: BN2 affine -> maxpool4 -> conv3+ELU -> convp+ELU -> BN3 partials -> maxpool5 ----------------
__global__ __launch_bounds__(256) void k3_mid(const float* __restrict__ C,
    const float* __restrict__ w3, const float* __restrict__ b3,
    const float* __restrict__ wp, const float* __restrict__ bp,
    const float* __restrict__ z2, float* __restrict__ P, float* __restrict__ partial3)
{
  __shared__ float pbuf[4][74*8];
  __shared__ float qbuf[4][50*8];
  __shared__ float wbuf[4][50*8];
  __shared__ float wred[4][16];
  const int tid = threadIdx.x, lane = tid & 63, wid = tid >> 6;
  const int b = blockIdx.x*4 + wid;
  const int ts = lane >> 3, oo = lane & 7;
  float* pb = pbuf[wid]; float* qb = qbuf[wid]; float* wb = wbuf[wid];
  for (int i = lane; i < 96; i += 64) { pb[i] = 0.f; pb[62*8 + i] = 0.f; }
  const float* zb = z2 + (size_t)b*TLEN*8;
  const float s2o = C[C2_OFF + oo], d2o = C[C2_OFF + 8 + oo];
  for (int tp = ts; tp < 50; tp += 8) {
    float m = -1e30f;
    #pragma unroll
    for (int q = 0; q < 4; ++q) m = fmaxf(m, s2o * zb[(4*tp+q)*8 + oo] + d2o);
    pb[(12+tp)*8 + oo] = m;
  }
  __threadfence_block();
  for (int tp = ts; tp < 50; tp += 8) {
    float a = b3[oo];
    #pragma unroll 5
    for (int k = 0; k < 25; ++k) a += w3[oo*25+k] * pb[(tp+k)*8 + oo];
    qb[tp*8+oo] = eluf(a);
  }
  __threadfence_block();
  float sw = 0.f, sqw = 0.f;
  for (int tp = ts; tp < 50; tp += 8) {
    float a = bp[oo];
    #pragma unroll
    for (int i = 0; i < 8; ++i) a += wp[oo*8+i]*qb[tp*8+i];
    float w = eluf(a);
    wb[tp*8+oo] = w;
    sw += w; sqw += w*w;
  }
  __threadfence_block();
  for (int t2 = ts; t2 < 10; t2 += 8) {
    float m = -1e30f;
    #pragma unroll
    for (int q = 0; q < 5; ++q) m = fmaxf(m, wb[(5*t2+q)*8 + oo]);
    P[((size_t)oo*10 + t2)*BATCH + b] = m;
  }
  sw += __shfl_xor(sw, 8);  sqw += __shfl_xor(sqw, 8);
  sw += __shfl_xor(sw, 16); sqw += __shfl_xor(sqw, 16);
  sw += __shfl_xor(sw, 32); sqw += __shfl_xor(sqw, 32);
  if (lane < 8) { wred[wid][oo] = sw; wred[wid][8+oo] = sqw; }
  __syncthreads();
  if (tid < 16)
    partial3[(size_t)blockIdx.x*16 + tid] = wred[0][tid]+wred[1][tid]+wred[2][tid]+wred[3][tid];
}

// ---------------- KR3: fold BN3 stats ----------------
__global__ __launch_bounds__(256) void kr3(const float* __restrict__ partial3,
    const float* __restrict__ g3, const float* __restrict__ be3, float* __restrict__ C)
{
  __shared__ double dred[256];
  const int tid = threadIdx.x;
  const int t = tid & 15, chunk = tid >> 4;       // 16 chunks x 32
  double s = 0.0;
  for (int i = 0; i < 32; ++i) s += (double)partial3[(size_t)(chunk*32 + i)*16 + t];
  dred[tid] = s;
  __syncthreads();
  if (tid < 8) {
    double S = 0.0, SS = 0.0;
    for (int ch = 0; ch < 16; ++ch) { S += dred[ch*16 + tid]; SS += dred[ch*16 + 8 + tid]; }
    const double N = 2048.0*50.0;
    double m = S/N, var = fmax(SS/N - m*m, 1e-20);
    double sc = (double)g3[tid] / sqrt(var);
    C[C3_OFF + tid] = (float)sc;
    C[C3_OFF + 8 + tid] = (float)((double)be3[tid] - m*sc);
  }
}

// ---------------- K4: per-branch biLSTM (fwd 10 steps; bwd = 1 step) + BN-l partials ----------------
__global__ __launch_bounds__(512) void k4_lstm(const float* __restrict__ wih,
    const float* __restrict__ whh, const float* __restrict__ bih, const float* __restrict__ bhh,
    const float* __restrict__ C, const float* __restrict__ P,
    float* __restrict__ feats, float* __restrict__ partialL)
{
  __shared__ float hsh[2][HID*64];
  __shared__ float csh[HID*64];
  const int tid = threadIdx.x, lane = tid & 63, wid = tid >> 6;
  const int k = blockIdx.x >> 5, tile = blockIdx.x & 31;
  const int b = tile*64 + lane;
  const int us = __builtin_amdgcn_readfirstlane(wid * 15);
  const float s3 = C[C3_OFF + k], d3 = C[C3_OFF + 8 + k];
  const float* whh_k = whh + (size_t)(k*2)*480*120;
  const float* wih_k = wih + (size_t)(k*2)*480;
  const float* bih_k = bih + (size_t)(k*2)*480;
  const float* bhh_k = bhh + (size_t)(k*2)*480;
  const float* Pk = P + (size_t)k*10*BATCH;
  float* partL = partialL + (size_t)blockIdx.x*480;
  #pragma unroll
  for (int ui = 0; ui < 15; ++ui) csh[(us+ui)*64 + lane] = 0.f;
  __syncthreads();
  for (int t = 0; t < 10; ++t) {
    const int rb = t & 1, wbuf = rb ^ 1;
    const float xv = s3 * Pk[t*BATCH + b] + d3;
    for (int ug = 0; ug < 3; ++ug) {
      float a0[5], a1[5], a2[5], a3[5];
      #pragma unroll
      for (int uu = 0; uu < 5; ++uu) {
        const int u = us + ug*5 + uu;
        a0[uu] = bih_k[u]     + bhh_k[u]     + xv * wih_k[u];
        a1[uu] = bih_k[120+u] + bhh_k[120+u] + xv * wih_k[120+u];
        a2[uu] = bih_k[240+u] + bhh_k[240+u] + xv * wih_k[240+u];
        a3[uu] = bih_k[360+u] + bhh_k[360+u] + xv * wih_k[360+u];
      }
      if (t > 0) {
        const float* hb = hsh[rb];
        #pragma unroll 4
        for (int j = 0; j < 120; ++j) {
          const float hv = hb[j*64 + lane];
          #pragma unroll
          for (int uu = 0; uu < 5; ++uu) {
            const int u = us + ug*5 + uu;
            a0[uu] += whh_k[(      u)*120 + j] * hv;
            a1[uu] += whh_k[(120 + u)*120 + j] * hv;
            a2[uu] += whh_k[(240 + u)*120 + j] * hv;
            a3[uu] += whh_k[(360 + u)*120 + j] * hv;
          }
        }
      }
      #pragma unroll
      for (int uu = 0; uu < 5; ++uu) {
        const int u = us + ug*5 + uu;
        float ig = sigmf(a0[uu]), fg = sigmf(a1[uu]);
        float gg = tanhf_fast(a2[uu]), og = sigmf(a3[uu]);
        float c = fg * csh[u*64+lane] + ig * gg;
        csh[u*64+lane] = c;
        hsh[wbuf][u*64+lane] = og * tanhf_fast(c);
      }
    }
    __syncthreads();
  }
  const size_t frow = ((size_t)k*BATCH + b)*240;
  #pragma unroll
  for (int ui = 0; ui < 15; ++ui) {
    const int u = us + ui;
    float v = hsh[0][u*64 + lane];
    feats[frow + u] = v;
    float s = v, sq = v*v;
    for (int m = 32; m; m >>= 1) { s += __shfl_xor(s, m); sq += __shfl_xor(sq, m); }
    if (lane == 0) { partL[u] = s; partL[240 + u] = sq; }
  }
  const float x9 = s3 * Pk[9*BATCH + b] + d3;
  const float* wihB = wih_k + 480;
  const float* bihB = bih_k + 480;
  const float* bhhB = bhh_k + 480;
  #pragma unroll
  for (int ui = 0; ui < 15; ++ui) {
    const int u = us + ui;
    float zi = bihB[u]     + bhhB[u]     + x9*wihB[u];
    float zg = bihB[240+u] + bhhB[240+u] + x9*wihB[240+u];
    float zo = bihB[360+u] + bhhB[360+u] + x9*wihB[360+u];
    float c = sigmf(zi) * tanhf_fast(zg);
    float v = sigmf(zo) * tanhf_fast(c);
    feats[frow + 120 + u] = v;
    float s = v, sq = v*v;
    for (int m = 32; m; m >>= 1) { s += __shfl_xor(s, m); sq += __shfl_xor(sq, m); }
    if (lane == 0) { partL[120 + u] = s; partL[240 + 120 + u] = sq; }
  }
}

// ---------------- KR4: fold BN-l stats; emit head coeffs A and per-k Bsum (no cross-lane ops) ----------------
__global__ __launch_bounds__(256) void kr4(const float* __restrict__ partialL,
    const float* __restrict__ glx, const float* __restrict__ blx,
    const float* __restrict__ hw, float* __restrict__ C)
{
  __shared__ double bred[256];
  const int tid = threadIdx.x;
  const int k = blockIdx.x;
  double Bc = 0.0;
  if (tid < 240) {
    double s = 0.0, ss = 0.0;
    for (int tile = 0; tile < 32; ++tile) {
      const float* p = partialL + (size_t)(k*32 + tile)*480;
      s += (double)p[tid]; ss += (double)p[240 + tid];
    }
    double m = s/2048.0, var = fmax(ss/2048.0 - m*m, 1e-20);
    double sg = (double)glx[k*240+tid] / sqrt(var);
    double w  = (double)hw[k*240+tid];
    C[CL_OFF + k*240 + tid] = (float)(sg * w);
    Bc = ((double)blx[k*240+tid] - m*sg) * w;
  }
  bred[tid] = Bc;
  __syncthreads();
  if (tid == 0) {
    double t = 0.0;
    for (int i = 0; i < 240; ++i) t += bred[i];
    C[CL_OFF + 1920 + k] = (float)t;
  }
}

// ---------------- K5: head dot (BN-l folded) + ReLU; BN-o partials ----------------
// NOTE: Bsum is the FULL fold over d (from kr4) — add it ONCE after the lane
// reduce, NOT per-lane before it (per-lane init counted it 64x in R2/R4).
__global__ __launch_bounds__(256) void k5_head(const float* __restrict__ C,
    const float* __restrict__ hbias, const float* __restrict__ feats,
    float* __restrict__ hb_out, float* __restrict__ partialO)
{
  __shared__ float hred[8];
  const int tid = threadIdx.x, lane = tid & 63, wid = tid >> 6;
  const int row0 = blockIdx.x * 32;
  const int k = row0 >> 11;
  const float Bsum = C[CL_OFF + 1920 + k];
  const float hb_k = hbias[k];
  float A[4];
  #pragma unroll
  for (int r = 0; r < 4; ++r) {
    int d = lane + r*64;
    A[r] = (d < 240) ? C[CL_OFF + k*240 + d] : 0.f;
  }
  float hs = 0.f, hss = 0.f;
  for (int rr = 0; rr < 8; ++rr) {
    const int row = row0 + wid*8 + rr;
    const int b = row & 2047;
    const float* fr = feats + (size_t)row*240;
    float dot = 0.f;
    #pragma unroll
    for (int r = 0; r < 4; ++r) {
      int d = lane + r*64;
      if (d < 240) dot += fr[d] * A[r];
    }
    for (int m = 32; m; m >>= 1) dot += __shfl_xor(dot, m);
    float hv = fmaxf(dot + Bsum + hb_k, 0.f);
    if (lane == 0) hb_out[(size_t)k*BATCH + b] = hv;
    hs += hv; hss += hv*hv;
  }
  if (lane == 0) { hred[wid] = hs; hred[4+wid] = hss; }
  __syncthreads();
  if (tid == 0) {
    partialO[(size_t)blockIdx.x*2]     = hred[0]+hred[1]+hred[2]+hred[3];
    partialO[(size_t)blockIdx.x*2 + 1] = hred[4]+hred[5]+hred[6]+hred[7];
  }
}

// ---------------- KR5: fold BN-o stats (serial per branch, no cross-lane ops) ----------------
__global__ __launch_bounds__(64) void kr5(const float* __restrict__ partialO, float* __restrict__ C)
{
  const int lane = threadIdx.x;
  if (lane < 8) {
    double s = 0.0, ss = 0.0;
    for (int i = 0; i < 64; ++i) {
      s  += (double)partialO[(size_t)(lane*64 + i)*2];
      ss += (double)partialO[(size_t)(lane*64 + i)*2 + 1];
    }
    double m = s/2048.0, var = fmax(ss/2048.0 - m*m, 1e-20);
    C[CO_OFF + lane] = (float)m;
    C[CO_OFF + 8 + lane] = (float)(1.0 / sqrt(var));
  }
}

// ---------------- K6: BN-o affine + final dot + sigmoid ----------------
__global__ __launch_bounds__(256) void k6_out(const float* __restrict__ go, const float* __restrict__ bo,
    const float* __restrict__ ow, const float* __restrict__ ob,
    const float* __restrict__ hb_in, const float* __restrict__ C, float* __restrict__ out)
{
  const int b = blockIdx.x*256 + threadIdx.x;
  float acc = ob[0];
  #pragma unroll
  for (int k = 0; k < 8; ++k) {
    float m = C[CO_OFF + k], rs = C[CO_OFF + 8 + k];
    float z = hb_in[(size_t)k*BATCH + b];
    acc += ((z - m)*rs*go[k] + bo[k]) * ow[k];
  }
  out[b] = 1.f/(1.f + __expf(-acc));
}

extern "C" void kernel_launch(void* const* d_in, const int* in_sizes, int n_in,
                              void* d_out, int out_size, void* d_ws, size_t ws_size,
                              hipStream_t stream)
{
  (void)in_sizes; (void)n_in; (void)out_size; (void)ws_size;
  const float* x    = (const float*)d_in[0];
  const float* w1   = (const float*)d_in[1];
  const float* b1   = (const float*)d_in[2];
  const float* g1   = (const float*)d_in[3];
  const float* be1  = (const float*)d_in[4];
  const float* w2   = (const float*)d_in[5];
  const float* b2   = (const float*)d_in[6];
  const float* g2   = (const float*)d_in[7];
  const float* be2  = (const float*)d_in[8];
  const float* w3   = (const float*)d_in[9];
  const float* b3   = (const float*)d_in[10];
  const float* wp   = (const float*)d_in[11];
  const float* bp   = (const float*)d_in[12];
  const float* g3   = (const float*)d_in[13];
  const float* be3  = (const float*)d_in[14];
  const float* wih  = (const float*)d_in[15];
  const float* whh  = (const float*)d_in[16];
  const float* bihp = (const float*)d_in[17];
  const float* bhhp = (const float*)d_in[18];
  const float* glx  = (const float*)d_in[19];
  const float* blx  = (const float*)d_in[20];
  const float* hw   = (const float*)d_in[21];
  const float* hbi  = (const float*)d_in[22];
  const float* go   = (const float*)d_in[23];
  const float* bo   = (const float*)d_in[24];
  const float* ow   = (const float*)d_in[25];
  const float* ob   = (const float*)d_in[26];

  float* ws    = (float*)d_ws;
  float* C     = ws;                 // constants region (C1/C2/C3/CO/CL)
  float* p1    = ws + P1_OFF;
  float* p2    = ws + P2_OFF;
  float* p3    = ws + P3_OFF;
  float* pO    = ws + PO_OFF;
  float* pL    = ws + PL_OFF;
  float* P     = ws + P_OFF;
  float* hbuf  = ws + HB_OFF;
  float* rz    = ws + A_OFF;         // conv2 raw dot, then z2 in-place
  float* feats = ws + A_OFF;         // reuses region after K3 consumed z2
  float* out   = (float*)d_out;

  k1_conv<<<2048, 256, 0, stream>>>(x, w1, b1, w2, rz, p1);
  kr1<<<1, 64, 0, stream>>>(p1, g1, be1, w2, b2, C);
  k2_elu<<<1600, 256, 0, stream>>>(C, rz, p2);
  kr2<<<1, 256, 0, stream>>>(p2, g2, be2, C);
  k3_mid<<<512, 256, 0, stream>>>(C, w3, b3, wp, bp, rz, P, p3);
  kr3<<<1, 256, 0, stream>>>(p3, g3, be3, C);
  k4_lstm<<<256, 512, 0, stream>>>(wih, whh, bihp, bhhp, C, P, feats, pL);
  kr4<<<8, 256, 0, stream>>>(pL, glx, blx, hw, C);
  k5_head<<<512, 256, 0, stream>>>(C, hbi, feats, hbuf, pO);
  kr5<<<1, 64, 0, stream>>>(pO, C);
  k6_out<<<8, 256, 0, stream>>>(go, bo, ow, ob, hbuf, C, out);
}